// Round 12
// baseline (722.084 us; speedup 1.0000x reference)
//
#include <hip/hip_runtime.h>
#include <math.h>

constexpr int Bn = 64;
constexpr int Dn = 1024;
constexpr int NBK = 128;
constexpr float LOG2E = 1.4426950408889634f;
constexpr float LN2   = 0.6931471805599453f;
constexpr int PROBE_REPS = 16;

__device__ __forceinline__ float exp2_fast(float v) {
#if defined(__has_builtin)
#if __has_builtin(__builtin_amdgcn_exp2f)
  return __builtin_amdgcn_exp2f(v);
#else
  return exp2f(v);
#endif
#else
  return exp2f(v);
#endif
}

// ---------------------------------------------------------------------------
// MEASUREMENT ROUND — phase-ablation probes.  Round-10/11 evidence: sortsoft
// responds to neither 2x TLP nor halved serial chains -> bound by a shared
// per-CU throughput resource, phase unknown.  kprobe<P> runs PROBE_REPS of
// the v6 body's phase-prefix P: 1 = count+scan, 2 = +scatter, 3 = +Bsum+desc,
// 4 = full softmax.  Each surfaces as its own dispatch row; marginals give
// the phase split.  Probes write keep-alive results to scratch (ws+4MB);
// the unchanged production pipeline runs afterward.
// ---------------------------------------------------------------------------
template <int P>
__global__ __launch_bounds__(512) void kprobe(
    const float* __restrict__ x, float* __restrict__ scratch) {
  __shared__ float  xs_[Dn];
  __shared__ float2 prs_[Dn];
  __shared__ int    bkt_[Dn];
  __shared__ float4 desc_[128];
  __shared__ int   cnt[NBK], base_[NBK], off_[NBK];
  __shared__ float Ssum[NBK], cN[NBK], cS[NBK];
  __shared__ float redM[8][64], redE[8][64], redD[8][64];

  int b   = blockIdx.x >> 4;
  int rc  = blockIdx.x & 15;
  int tid = threadIdx.x;
  float result = 0.f;

  for (int rep = 0; rep < PROBE_REPS; ++rep) {
    if (tid < NBK) { cnt[tid] = 0; off_[tid] = 0; Ssum[tid] = 0.f; }
    __syncthreads();

    // ---- phase 1: bucket count (atomics) + dual scan ----
    float2 v2 = *(const float2*)(x + b * Dn + tid * 2);
    float xv[2] = {v2.x, v2.y};
    int bk[2];
#pragma unroll
    for (int u = 0; u < 2; ++u) {
      float z = exp2_fast(-2.455532f * xv[u]);
      float p = 1.f / (1.f + z);
      int t = (int)(p * 128.f);
      bk[u] = t < 0 ? 0 : (t > 127 ? 127 : t);
      atomicAdd(&cnt[bk[u]], 1);
      atomicAdd(&Ssum[bk[u]], xv[u]);
    }
    __syncthreads();

    if (tid < 64) {
      int c0 = cnt[tid], c1 = cnt[tid + 64];
      float f0 = Ssum[tid], f1 = Ssum[tid + 64];
      int s0 = c0, s1 = c1;
      float g0 = f0, g1 = f1;
#pragma unroll
      for (int d = 1; d < 64; d <<= 1) {
        int o0 = __shfl_up(s0, d, 64), o1 = __shfl_up(s1, d, 64);
        float h0 = __shfl_up(g0, d, 64), h1 = __shfl_up(g1, d, 64);
        if (tid >= d) { s0 += o0; s1 += o1; g0 += h0; g1 += h1; }
      }
      int   T0 = __shfl(s0, 63, 64);
      float G0 = __shfl(g0, 63, 64);
      float G1 = __shfl(g1, 63, 64);
      float Stot = G0 + G1;
      int nlo0 = s0 - c0;
      base_[tid] = nlo0;
      cN[tid] = (float)(2 * nlo0 + c0 - Dn);
      float slo0 = g0 - f0;
      cS[tid] = Stot - 2.f * slo0 - f0;
      int nlo1 = T0 + s1 - c1;
      base_[tid + 64] = nlo1;
      cN[tid + 64] = (float)(2 * nlo1 + c1 - Dn);
      float slo1 = G0 + g1 - f1;
      cS[tid + 64] = Stot - 2.f * slo1 - f1;
    }
    __syncthreads();

    if constexpr (P >= 2) {
      // ---- phase 2: scatter (atomic offsets) ----
#pragma unroll
      for (int u = 0; u < 2; ++u) {
        int pos = base_[bk[u]] + atomicAdd(&off_[bk[u]], 1);
        xs_[pos] = xv[u];
        bkt_[pos] = bk[u];
      }
      __syncthreads();
    }

    if constexpr (P >= 3) {
      // ---- phase 3: Bsum + desc ----
#pragma unroll
      for (int r = 0; r < 2; ++r) {
        int p = r * 512 + tid;
        float xp = xs_[p];
        int q = bkt_[p];
        int lo = base_[q], hi = lo + cnt[q];
        float local = 0.f;
        for (int k = lo; k < hi; ++k) local += fabsf(xp - xs_[k]);
        float Bs = fmaf(xp, cN[q], cS[q]) + local;
        prs_[p] = make_float2(xp * LOG2E, -Bs * LOG2E);
      }
      __syncthreads();
      if (tid < 128) {
        int base = tid * 8;
        float xlo = xs_[base], xhi = xlo;
        int ilo = base, ihi = base;
#pragma unroll
        for (int k = 1; k < 8; ++k) {
          float xx = xs_[base + k];
          if (xx < xlo) { xlo = xx; ilo = base + k; }
          if (xx > xhi) { xhi = xx; ihi = base + k; }
        }
        float2 plo = prs_[ilo], phi = prs_[ihi];
        desc_[tid] = make_float4(plo.x, plo.y, phi.x, phi.y);
      }
      __syncthreads();
    }

    if constexpr (P >= 4) {
      // ---- phase 4: M pass + votes + exp + reduce ----
      int w = tid >> 6, lane = tid & 63;
      int i = rc * 64 + lane;
      float sc = (float)(Dn - 1 - 2 * i);
      float gm[16];
      float m = -3.4e38f;
#pragma unroll 8
      for (int q = 0; q < 16; ++q) {
        float4 d = desc_[q * 8 + w];
        float t0 = fmaf(sc, d.x, d.y);
        float t1 = fmaf(sc, d.z, d.w);
        float g = fmaxf(t0, t1);
        gm[q] = g;
        m = fmaxf(m, g);
      }
      redM[w][lane] = m;
      __syncthreads();
      float M = fmaxf(fmaxf(fmaxf(redM[0][lane], redM[1][lane]),
                            fmaxf(redM[2][lane], redM[3][lane])),
                      fmaxf(fmaxf(redM[4][lane], redM[5][lane]),
                            fmaxf(redM[6][lane], redM[7][lane])));
      float thresh = M - 32.f;
      float se = 0.f, sd = 0.f;
#pragma unroll 4
      for (int q = 0; q < 16; ++q) {
        if (__any(gm[q] > thresh)) {
          int base = (q * 8 + w) * 8;
#pragma unroll
          for (int u = 0; u < 8; ++u) {
            float2 v = prs_[base + u];
            float e = exp2_fast(fmaf(sc, v.x, v.y - M));
            se += e;
            sd = fmaf(e, v.x, sd);
          }
        }
      }
      redE[w][lane] = se;
      redD[w][lane] = sd;
      __syncthreads();
      result = se + sd;
      if (tid < 64) {
        float SE = ((redE[0][lane] + redE[1][lane]) + (redE[2][lane] + redE[3][lane])) +
                   ((redE[4][lane] + redE[5][lane]) + (redE[6][lane] + redE[7][lane]));
        float SD = ((redD[0][lane] + redD[1][lane]) + (redD[2][lane] + redD[3][lane])) +
                   ((redD[4][lane] + redD[5][lane]) + (redD[6][lane] + redD[7][lane]));
        result = SD / SE;
      }
    }
    __syncthreads();
  }

  // keep-alive writes (defeat DCE; rule #17)
  if constexpr (P == 1) result = cN[tid & 127] + cS[tid & 127] + (float)base_[tid & 127];
  if constexpr (P == 2) result = xs_[tid] + (float)bkt_[tid];
  if constexpr (P == 3) result = prs_[tid].y + desc_[tid & 127].x;
  scratch[(size_t)blockIdx.x * 512 + tid] = result;
}

// ---------------------------------------------------------------------------
// K_SORTSOFT v6 (round-11 production version, verbatim).
// ---------------------------------------------------------------------------
__global__ __launch_bounds__(512) void k_sortsoft(
    const float* __restrict__ x, float* __restrict__ xs_out,
    float* __restrict__ out) {
  __shared__ float  xs_[Dn];
  __shared__ float2 prs_[Dn];
  __shared__ int    bkt_[Dn];
  __shared__ float4 desc_[128];
  __shared__ int   cnt[NBK], base_[NBK], off_[NBK];
  __shared__ float Ssum[NBK], cN[NBK], cS[NBK];
  __shared__ float redM[8][64], redE[8][64], redD[8][64];

  int b   = blockIdx.x >> 4;
  int rc  = blockIdx.x & 15;
  int tid = threadIdx.x;

  if (tid < NBK) { cnt[tid] = 0; off_[tid] = 0; Ssum[tid] = 0.f; }
  if (blockIdx.x == 0 && tid < 128) out[tid] = 0.f;
  __syncthreads();

  float2 v2 = *(const float2*)(x + b * Dn + tid * 2);
  float xv[2] = {v2.x, v2.y};
  int bk[2];
#pragma unroll
  for (int u = 0; u < 2; ++u) {
    float z = exp2_fast(-2.455532f * xv[u]);
    float p = 1.f / (1.f + z);
    int t = (int)(p * 128.f);
    bk[u] = t < 0 ? 0 : (t > 127 ? 127 : t);
    atomicAdd(&cnt[bk[u]], 1);
    atomicAdd(&Ssum[bk[u]], xv[u]);
  }
  __syncthreads();

  if (tid < 64) {
    int c0 = cnt[tid], c1 = cnt[tid + 64];
    float f0 = Ssum[tid], f1 = Ssum[tid + 64];
    int s0 = c0, s1 = c1;
    float g0 = f0, g1 = f1;
#pragma unroll
    for (int d = 1; d < 64; d <<= 1) {
      int o0 = __shfl_up(s0, d, 64), o1 = __shfl_up(s1, d, 64);
      float h0 = __shfl_up(g0, d, 64), h1 = __shfl_up(g1, d, 64);
      if (tid >= d) { s0 += o0; s1 += o1; g0 += h0; g1 += h1; }
    }
    int   T0 = __shfl(s0, 63, 64);
    float G0 = __shfl(g0, 63, 64);
    float G1 = __shfl(g1, 63, 64);
    float Stot = G0 + G1;
    int nlo0 = s0 - c0;
    base_[tid] = nlo0;
    cN[tid] = (float)(2 * nlo0 + c0 - Dn);
    float slo0 = g0 - f0;
    cS[tid] = Stot - 2.f * slo0 - f0;
    int nlo1 = T0 + s1 - c1;
    base_[tid + 64] = nlo1;
    cN[tid + 64] = (float)(2 * nlo1 + c1 - Dn);
    float slo1 = G0 + g1 - f1;
    cS[tid + 64] = Stot - 2.f * slo1 - f1;
  }
  __syncthreads();

#pragma unroll
  for (int u = 0; u < 2; ++u) {
    int pos = base_[bk[u]] + atomicAdd(&off_[bk[u]], 1);
    xs_[pos] = xv[u];
    bkt_[pos] = bk[u];
  }
  __syncthreads();

#pragma unroll
  for (int r = 0; r < 2; ++r) {
    int p = r * 512 + tid;
    float xp = xs_[p];
    int q = bkt_[p];
    int lo = base_[q], hi = lo + cnt[q];
    float local = 0.f;
    for (int k = lo; k < hi; ++k) local += fabsf(xp - xs_[k]);
    float Bs = fmaf(xp, cN[q], cS[q]) + local;
    prs_[p] = make_float2(xp * LOG2E, -Bs * LOG2E);
  }
  __syncthreads();

  if (tid < 128) {
    int base = tid * 8;
    float xlo = xs_[base], xhi = xlo;
    int ilo = base, ihi = base;
#pragma unroll
    for (int k = 1; k < 8; ++k) {
      float xx = xs_[base + k];
      if (xx < xlo) { xlo = xx; ilo = base + k; }
      if (xx > xhi) { xhi = xx; ihi = base + k; }
    }
    float2 plo = prs_[ilo], phi = prs_[ihi];
    desc_[tid] = make_float4(plo.x, plo.y, phi.x, phi.y);
  }
  __syncthreads();

  int w = tid >> 6, lane = tid & 63;
  int i = rc * 64 + lane;
  float sc = (float)(Dn - 1 - 2 * i);
  float gm[16];
  float m = -3.4e38f;
#pragma unroll 8
  for (int q = 0; q < 16; ++q) {
    float4 d = desc_[q * 8 + w];
    float t0 = fmaf(sc, d.x, d.y);
    float t1 = fmaf(sc, d.z, d.w);
    float g = fmaxf(t0, t1);
    gm[q] = g;
    m = fmaxf(m, g);
  }
  redM[w][lane] = m;
  __syncthreads();
  float M = fmaxf(fmaxf(fmaxf(redM[0][lane], redM[1][lane]),
                        fmaxf(redM[2][lane], redM[3][lane])),
                  fmaxf(fmaxf(redM[4][lane], redM[5][lane]),
                        fmaxf(redM[6][lane], redM[7][lane])));
  float thresh = M - 32.f;

  float se = 0.f, sd = 0.f;
#pragma unroll 4
  for (int q = 0; q < 16; ++q) {
    if (__any(gm[q] > thresh)) {
      int base = (q * 8 + w) * 8;
#pragma unroll
      for (int u = 0; u < 8; ++u) {
        float2 v = prs_[base + u];
        float e = exp2_fast(fmaf(sc, v.x, v.y - M));
        se += e;
        sd = fmaf(e, v.x, sd);
      }
    }
  }
  redE[w][lane] = se;
  redD[w][lane] = sd;
  __syncthreads();
  if (tid < 64) {
    float SE = ((redE[0][lane] + redE[1][lane]) + (redE[2][lane] + redE[3][lane])) +
               ((redE[4][lane] + redE[5][lane]) + (redE[6][lane] + redE[7][lane]));
    float SD = ((redD[0][lane] + redD[1][lane]) + (redD[2][lane] + redD[3][lane])) +
               ((redD[4][lane] + redD[5][lane]) + (redD[6][lane] + redD[7][lane]));
    xs_out[b * Dn + rc * 64 + lane] = SD / SE * LN2;
  }
}

// ---------------------------------------------------------------------------
// Layer kernel v4 (round-8 version, verbatim).
// ---------------------------------------------------------------------------
template <bool TAIL>
__global__ __launch_bounds__(256) void layer_kernel(
    const float* __restrict__ in, const float* __restrict__ W,
    const float* __restrict__ bias, float* __restrict__ out,
    const float* __restrict__ W3, const float* __restrict__ b3,
    float* __restrict__ out2) {
  __shared__ float s[8 * Dn];
  __shared__ float rk[4][32];
  __shared__ float r2[8][8][2];
  int xcd = blockIdx.x & 7;
  int idx = blockIdx.x >> 3;
  int nc = xcd * 16 + (idx & 15);
  int bc = idx >> 4;
  int tid = threadIdx.x;
  const float* src = in + bc * 8 * Dn;
#pragma unroll
  for (int u = 0; u < 8; ++u) {
    int gl = u * 256 + tid;
    int r = gl >> 8, g = gl & 255;
    int gs = g ^ ((g >> 3) & 7);
    *(float4*)&s[r * Dn + gs * 4] = *(const float4*)(src + gl * 4);
  }
  __syncthreads();

  int w = tid >> 6, lane = tid & 63;
  int cq = w & 1, kh = w >> 1;
  int n0 = nc * 8 + cq * 4;
  const float* wp = W + (size_t)n0 * Dn + kh * 512 + lane * 8;
  float acc[32];
#pragma unroll
  for (int i = 0; i < 32; ++i) acc[i] = 0.f;
#pragma unroll
  for (int j = 0; j < 2; ++j) {
    float4 wv0 = *(const float4*)(wp + 0 * Dn + j * 4);
    float4 wv1 = *(const float4*)(wp + 1 * Dn + j * 4);
    float4 wv2 = *(const float4*)(wp + 2 * Dn + j * 4);
    float4 wv3 = *(const float4*)(wp + 3 * Dn + j * 4);
    int g = kh * 128 + lane * 2 + j;
    int gs = g ^ ((g >> 3) & 7);
    const float* sp = s + gs * 4;
#pragma unroll
    for (int bl = 0; bl < 8; ++bl) {
      float4 av = *(const float4*)(sp + bl * Dn);
      acc[bl * 4 + 0] = fmaf(av.x, wv0.x, fmaf(av.y, wv0.y,
                        fmaf(av.z, wv0.z, fmaf(av.w, wv0.w, acc[bl * 4 + 0]))));
      acc[bl * 4 + 1] = fmaf(av.x, wv1.x, fmaf(av.y, wv1.y,
                        fmaf(av.z, wv1.z, fmaf(av.w, wv1.w, acc[bl * 4 + 1]))));
      acc[bl * 4 + 2] = fmaf(av.x, wv2.x, fmaf(av.y, wv2.y,
                        fmaf(av.z, wv2.z, fmaf(av.w, wv2.w, acc[bl * 4 + 2]))));
      acc[bl * 4 + 3] = fmaf(av.x, wv3.x, fmaf(av.y, wv3.y,
                        fmaf(av.z, wv3.z, fmaf(av.w, wv3.w, acc[bl * 4 + 3]))));
    }
  }

#pragma unroll
  for (int bit = 0; bit < 5; ++bit) {
    int d = 1 << bit;
    bool hi = (lane & d) != 0;
#pragma unroll
    for (int i = 0; i < (16 >> bit); ++i) {
      float keep = hi ? acc[2 * i + 1] : acc[2 * i];
      float send = hi ? acc[2 * i] : acc[2 * i + 1];
      acc[i] = keep + __shfl_xor(send, d, 64);
    }
  }
  float t = acc[0];
  t += __shfl_xor(t, 32, 64);
  if (lane < 32) rk[w][lane] = t;
  __syncthreads();

  if (tid < 64) {
    int bl2 = tid >> 3, col = tid & 7;
    int cq2 = col >> 2, cl2 = col & 3;
    int o = bl2 * 4 + cl2;
    int n2 = nc * 8 + col;
    float hs = rk[cq2][o] + rk[cq2 + 2][o];
    float h = hs + bias[n2];
    h = h >= 0.f ? h : 0.01f * h;
    if (!TAIL) {
      out[(bc * 8 + bl2) * Dn + n2] = h;
    } else {
      r2[bl2][col][0] = h * W3[n2];
      r2[bl2][col][1] = h * W3[Dn + n2];
    }
  }
  if (TAIL) {
    __syncthreads();
    if (tid < 16) {
      int bl2 = tid >> 1, o = tid & 1;
      float tt = 0.f;
#pragma unroll
      for (int q = 0; q < 8; ++q) tt += r2[bl2][q][o];
      if (nc == 0) tt += b3[o];
      atomicAdd(out2 + (bc * 8 + bl2) * 2 + o, tt);
    }
  }
}

extern "C" void kernel_launch(void* const* d_in, const int* in_sizes, int n_in,
                              void* d_out, int out_size, void* d_ws, size_t ws_size,
                              hipStream_t stream) {
  const float* x  = (const float*)d_in[0];
  const float* W1 = (const float*)d_in[1];
  const float* b1 = (const float*)d_in[2];
  const float* W2 = (const float*)d_in[3];
  const float* b2 = (const float*)d_in[4];
  const float* W3 = (const float*)d_in[5];
  const float* b3 = (const float*)d_in[6];
  float* out = (float*)d_out;
  float* ws = (float*)d_ws;

  float* xs = ws;                          // 256 KB
  float* h1 = xs + Bn * Dn;                // 256 KB
  float* scratch = ws + (1 << 20);         // probe scratch at ws+4MB

  // ---- ablation probes (measurement only; outputs to scratch) ----
  kprobe<1><<<Bn * 16, 512, 0, stream>>>(x, scratch + 0 * (1 << 19));
  kprobe<2><<<Bn * 16, 512, 0, stream>>>(x, scratch + 1 * (1 << 19));
  kprobe<3><<<Bn * 16, 512, 0, stream>>>(x, scratch + 2 * (1 << 19));
  kprobe<4><<<Bn * 16, 512, 0, stream>>>(x, scratch + 3 * (1 << 19));

  // ---- production pipeline (round-11, unchanged) ----
  k_sortsoft<<<Bn * 16, 512, 0, stream>>>(x, xs, out);
  layer_kernel<false><<<1024, 256, 0, stream>>>(xs, W1, b1, h1,
                                                nullptr, nullptr, nullptr);
  layer_kernel<true><<<1024, 256, 0, stream>>>(h1, W2, b2, nullptr,
                                               W3, b3, out);
}

// Round 13
// 95.239 us; speedup vs baseline: 7.5818x; 7.5818x over previous
//
#include <hip/hip_runtime.h>
#include <math.h>

constexpr int Bn = 64;
constexpr int Dn = 1024;
constexpr int NBK = 128;
constexpr float LOG2E = 1.4426950408889634f;
constexpr float LN2   = 0.6931471805599453f;

__device__ __forceinline__ float exp2_fast(float v) {
#if defined(__has_builtin)
#if __has_builtin(__builtin_amdgcn_exp2f)
  return __builtin_amdgcn_exp2f(v);
#else
  return exp2f(v);
#endif
#else
  return exp2f(v);
#endif
}

// ---------------------------------------------------------------------------
// K_SORT: ONE block per batch b (64 blocks x 1024 threads).  Sort + Bsum +
// desc computed ONCE per b (was duplicated x16 inside the softmax kernel —
// round-12 probes show phases 1-3's LDS/VALU load spread is the remaining
// removable work).  Writes prs (float2, 8KB) + desc (float4, 2KB) per b to
// workspace (L2-resident for the 16 softmax blocks of this b).  Single block
// per b -> no cross-block scatter-order consistency hazard.  Low CU fill
// (25%) is acceptable: the kernel is tiny and latency-dominated either way.
// Zeroes d_out (block 0) for the tail layer's atomicAdds.
// ---------------------------------------------------------------------------
__global__ __launch_bounds__(1024) void k_sort(
    const float* __restrict__ x, float2* __restrict__ prs_g,
    float4* __restrict__ desc_g, float* __restrict__ out) {
  __shared__ float  xs_[Dn];
  __shared__ float2 prs_[Dn];
  __shared__ int    bkt_[Dn];
  __shared__ int   cnt[NBK], base_[NBK], off_[NBK];
  __shared__ float Ssum[NBK], cN[NBK], cS[NBK];

  int b   = blockIdx.x;
  int tid = threadIdx.x;

  if (tid < NBK) { cnt[tid] = 0; off_[tid] = 0; Ssum[tid] = 0.f; }
  if (b == 0 && tid < 128) out[tid] = 0.f;
  __syncthreads();

  // ---- bucket count (1 element per thread) ----
  float xv = x[b * Dn + tid];
  int bk;
  {
    float z = exp2_fast(-2.455532f * xv);      // 2^{-1.702 x log2e}, monotone
    float p = 1.f / (1.f + z);                 // ~Phi(x): near-uniform buckets
    int t = (int)(p * 128.f);
    bk = t < 0 ? 0 : (t > 127 ? 127 : t);
    atomicAdd(&cnt[bk], 1);
    atomicAdd(&Ssum[bk], xv);
  }
  __syncthreads();

  // ---- dual prefix scan over 128 buckets (wave 0, 2 buckets per lane) ----
  if (tid < 64) {
    int c0 = cnt[tid], c1 = cnt[tid + 64];
    float f0 = Ssum[tid], f1 = Ssum[tid + 64];
    int s0 = c0, s1 = c1;
    float g0 = f0, g1 = f1;
#pragma unroll
    for (int d = 1; d < 64; d <<= 1) {
      int o0 = __shfl_up(s0, d, 64), o1 = __shfl_up(s1, d, 64);
      float h0 = __shfl_up(g0, d, 64), h1 = __shfl_up(g1, d, 64);
      if (tid >= d) { s0 += o0; s1 += o1; g0 += h0; g1 += h1; }
    }
    int   T0 = __shfl(s0, 63, 64);
    float G0 = __shfl(g0, 63, 64);
    float G1 = __shfl(g1, 63, 64);
    float Stot = G0 + G1;
    int nlo0 = s0 - c0;
    base_[tid] = nlo0;
    cN[tid] = (float)(2 * nlo0 + c0 - Dn);     // Nlo - Nhi
    float slo0 = g0 - f0;
    cS[tid] = Stot - 2.f * slo0 - f0;          // Shi - Slo
    int nlo1 = T0 + s1 - c1;
    base_[tid + 64] = nlo1;
    cN[tid + 64] = (float)(2 * nlo1 + c1 - Dn);
    float slo1 = G0 + g1 - f1;
    cS[tid + 64] = Stot - 2.f * slo1 - f1;
  }
  __syncthreads();

  // ---- scatter ----
  {
    int pos = base_[bk] + atomicAdd(&off_[bk], 1);
    xs_[pos] = xv;
    bkt_[pos] = bk;
  }
  __syncthreads();

  // ---- exact Bsum per position (1 per thread; ~8-iter bucket loop) ----
  {
    float xp = xs_[tid];
    int q = bkt_[tid];
    int lo = base_[q], hi = lo + cnt[q];
    float local = 0.f;
    for (int k = lo; k < hi; ++k) local += fabsf(xp - xs_[k]);
    float Bs = fmaf(xp, cN[q], cS[q]) + local;
    float2 pr = make_float2(xp * LOG2E, -Bs * LOG2E);
    prs_[tid] = pr;
    prs_g[(size_t)b * Dn + tid] = pr;          // coalesced float2 store
  }
  __syncthreads();

  // ---- group descriptors (one group of 8 per thread, 128 groups) ----
  if (tid < 128) {
    int base = tid * 8;
    float xlo = xs_[base], xhi = xlo;
    int ilo = base, ihi = base;
#pragma unroll
    for (int k = 1; k < 8; ++k) {
      float xx = xs_[base + k];
      if (xx < xlo) { xlo = xx; ilo = base + k; }
      if (xx > xhi) { xhi = xx; ihi = base + k; }
    }
    float2 plo = prs_[ilo], phi = prs_[ihi];
    desc_g[b * 128 + tid] = make_float4(plo.x, plo.y, phi.x, phi.y);
  }
}

// ---------------------------------------------------------------------------
// K_SOFT: softmax only (phase 4 of the former fused kernel, verbatim).
// grid = 64 b x 16 rc = 1024 blocks of 512.  Stages prs (8KB) + desc (2KB)
// from L2 into LDS with float4 loads (~0.3us), then the measured softsort:
// lane = row, 8 waves split the 128 groups 8-way (g = q*8 + w), concave
// endpoint bound + __any vote-skip over the same 64 consecutive rows.
// LDS 16KB -> thread-capacity-bound 4 blocks/CU (32 waves).
// ---------------------------------------------------------------------------
__global__ __launch_bounds__(512) void k_soft(
    const float2* __restrict__ prs_g, const float4* __restrict__ desc_g,
    float* __restrict__ xs_out) {
  __shared__ __align__(16) float2 prs_[Dn];
  __shared__ float4 desc_[128];
  __shared__ float redM[8][64], redE[8][64], redD[8][64];

  int b   = blockIdx.x >> 4;
  int rc  = blockIdx.x & 15;
  int tid = threadIdx.x;

  // ---- stage prs + desc into LDS ----
  ((float4*)prs_)[tid] = ((const float4*)(prs_g + (size_t)b * Dn))[tid];
  if (tid < 128) desc_[tid] = desc_g[b * 128 + tid];
  __syncthreads();

  int w = tid >> 6, lane = tid & 63;
  int i = rc * 64 + lane;
  float sc = (float)(Dn - 1 - 2 * i);          // exact in fp32
  float gm[16];
  float m = -3.4e38f;
#pragma unroll 8
  for (int q = 0; q < 16; ++q) {
    float4 d = desc_[q * 8 + w];               // wave-uniform broadcast
    float t0 = fmaf(sc, d.x, d.y);             // T at group's min-x element
    float t1 = fmaf(sc, d.z, d.w);             // T at group's max-x element
    float g = fmaxf(t0, t1);
    gm[q] = g;
    m = fmaxf(m, g);
  }
  redM[w][lane] = m;
  __syncthreads();
  float M = fmaxf(fmaxf(fmaxf(redM[0][lane], redM[1][lane]),
                        fmaxf(redM[2][lane], redM[3][lane])),
                  fmaxf(fmaxf(redM[4][lane], redM[5][lane]),
                        fmaxf(redM[6][lane], redM[7][lane])));
  float thresh = M - 32.f;

  float se = 0.f, sd = 0.f;
#pragma unroll 4
  for (int q = 0; q < 16; ++q) {
    if (__any(gm[q] > thresh)) {               // vote over 64 consecutive rows
      int base = (q * 8 + w) * 8;
#pragma unroll
      for (int u = 0; u < 8; ++u) {
        float2 v = prs_[base + u];             // wave-uniform broadcast
        float e = exp2_fast(fmaf(sc, v.x, v.y - M));
        se += e;
        sd = fmaf(e, v.x, sd);
      }
    }
  }
  redE[w][lane] = se;
  redD[w][lane] = sd;
  __syncthreads();
  if (tid < 64) {
    float SE = ((redE[0][lane] + redE[1][lane]) + (redE[2][lane] + redE[3][lane])) +
               ((redE[4][lane] + redE[5][lane]) + (redE[6][lane] + redE[7][lane]));
    float SD = ((redD[0][lane] + redD[1][lane]) + (redD[2][lane] + redD[3][lane])) +
               ((redD[4][lane] + redD[5][lane]) + (redD[6][lane] + redD[7][lane]));
    xs_out[b * Dn + rc * 64 + lane] = SD / SE * LN2;
  }
}

// ---------------------------------------------------------------------------
// Layer kernel v4 (round-8 version, verbatim).
// h = leaky(in @ W^T + bias).  Block = 8 batches x 8 cols.  Wave =
// (col-quad cq = w&1, k-half kh = w>>1); lane owns 8 k-floats; 1 B/FMA LDS.
// W loaded exactly once per block.  5-level routed butterfly + rk combine.
// Granule XOR swizzle g^((g>>3)&7).  XCD swizzle.  TAIL fuses layer 3.
// ---------------------------------------------------------------------------
template <bool TAIL>
__global__ __launch_bounds__(256) void layer_kernel(
    const float* __restrict__ in, const float* __restrict__ W,
    const float* __restrict__ bias, float* __restrict__ out,
    const float* __restrict__ W3, const float* __restrict__ b3,
    float* __restrict__ out2) {
  __shared__ float s[8 * Dn];
  __shared__ float rk[4][32];
  __shared__ float r2[8][8][2];
  int xcd = blockIdx.x & 7;
  int idx = blockIdx.x >> 3;
  int nc = xcd * 16 + (idx & 15);
  int bc = idx >> 4;
  int tid = threadIdx.x;
  const float* src = in + bc * 8 * Dn;
#pragma unroll
  for (int u = 0; u < 8; ++u) {
    int gl = u * 256 + tid;
    int r = gl >> 8, g = gl & 255;
    int gs = g ^ ((g >> 3) & 7);
    *(float4*)&s[r * Dn + gs * 4] = *(const float4*)(src + gl * 4);
  }
  __syncthreads();

  int w = tid >> 6, lane = tid & 63;
  int cq = w & 1, kh = w >> 1;
  int n0 = nc * 8 + cq * 4;
  const float* wp = W + (size_t)n0 * Dn + kh * 512 + lane * 8;
  float acc[32];
#pragma unroll
  for (int i = 0; i < 32; ++i) acc[i] = 0.f;
#pragma unroll
  for (int j = 0; j < 2; ++j) {
    float4 wv0 = *(const float4*)(wp + 0 * Dn + j * 4);
    float4 wv1 = *(const float4*)(wp + 1 * Dn + j * 4);
    float4 wv2 = *(const float4*)(wp + 2 * Dn + j * 4);
    float4 wv3 = *(const float4*)(wp + 3 * Dn + j * 4);
    int g = kh * 128 + lane * 2 + j;
    int gs = g ^ ((g >> 3) & 7);
    const float* sp = s + gs * 4;
#pragma unroll
    for (int bl = 0; bl < 8; ++bl) {
      float4 av = *(const float4*)(sp + bl * Dn);
      acc[bl * 4 + 0] = fmaf(av.x, wv0.x, fmaf(av.y, wv0.y,
                        fmaf(av.z, wv0.z, fmaf(av.w, wv0.w, acc[bl * 4 + 0]))));
      acc[bl * 4 + 1] = fmaf(av.x, wv1.x, fmaf(av.y, wv1.y,
                        fmaf(av.z, wv1.z, fmaf(av.w, wv1.w, acc[bl * 4 + 1]))));
      acc[bl * 4 + 2] = fmaf(av.x, wv2.x, fmaf(av.y, wv2.y,
                        fmaf(av.z, wv2.z, fmaf(av.w, wv2.w, acc[bl * 4 + 2]))));
      acc[bl * 4 + 3] = fmaf(av.x, wv3.x, fmaf(av.y, wv3.y,
                        fmaf(av.z, wv3.z, fmaf(av.w, wv3.w, acc[bl * 4 + 3]))));
    }
  }

#pragma unroll
  for (int bit = 0; bit < 5; ++bit) {
    int d = 1 << bit;
    bool hi = (lane & d) != 0;
#pragma unroll
    for (int i = 0; i < (16 >> bit); ++i) {
      float keep = hi ? acc[2 * i + 1] : acc[2 * i];
      float send = hi ? acc[2 * i] : acc[2 * i + 1];
      acc[i] = keep + __shfl_xor(send, d, 64);
    }
  }
  float t = acc[0];
  t += __shfl_xor(t, 32, 64);
  if (lane < 32) rk[w][lane] = t;
  __syncthreads();

  if (tid < 64) {
    int bl2 = tid >> 3, col = tid & 7;
    int cq2 = col >> 2, cl2 = col & 3;
    int o = bl2 * 4 + cl2;
    int n2 = nc * 8 + col;
    float hs = rk[cq2][o] + rk[cq2 + 2][o];
    float h = hs + bias[n2];
    h = h >= 0.f ? h : 0.01f * h;
    if (!TAIL) {
      out[(bc * 8 + bl2) * Dn + n2] = h;
    } else {
      r2[bl2][col][0] = h * W3[n2];
      r2[bl2][col][1] = h * W3[Dn + n2];
    }
  }
  if (TAIL) {
    __syncthreads();
    if (tid < 16) {
      int bl2 = tid >> 1, o = tid & 1;
      float tt = 0.f;
#pragma unroll
      for (int q = 0; q < 8; ++q) tt += r2[bl2][q][o];
      if (nc == 0) tt += b3[o];
      atomicAdd(out2 + (bc * 8 + bl2) * 2 + o, tt);
    }
  }
}

extern "C" void kernel_launch(void* const* d_in, const int* in_sizes, int n_in,
                              void* d_out, int out_size, void* d_ws, size_t ws_size,
                              hipStream_t stream) {
  const float* x  = (const float*)d_in[0];
  const float* W1 = (const float*)d_in[1];
  const float* b1 = (const float*)d_in[2];
  const float* W2 = (const float*)d_in[3];
  const float* b2 = (const float*)d_in[4];
  const float* W3 = (const float*)d_in[5];
  const float* b3 = (const float*)d_in[6];
  float* out = (float*)d_out;
  float* ws = (float*)d_ws;

  float*  xs     = ws;                          // 256 KB
  float*  h1     = xs + Bn * Dn;                // 256 KB
  float2* prs_g  = (float2*)(h1 + Bn * Dn);     // 512 KB
  float4* desc_g = (float4*)(prs_g + Bn * Dn);  // 32 KB

  k_sort<<<Bn, 1024, 0, stream>>>(x, prs_g, desc_g, out);
  k_soft<<<Bn * 16, 512, 0, stream>>>(prs_g, desc_g, xs);
  layer_kernel<false><<<1024, 256, 0, stream>>>(xs, W1, b1, h1,
                                                nullptr, nullptr, nullptr);
  layer_kernel<true><<<1024, 256, 0, stream>>>(h1, W2, b2, nullptr,
                                               W3, b3, out);
}

// Round 14
// 95.177 us; speedup vs baseline: 7.5867x; 1.0007x over previous
//
#include <hip/hip_runtime.h>
#include <math.h>

constexpr int Bn = 64;
constexpr int Dn = 1024;
constexpr int NBK = 128;
constexpr float LOG2E = 1.4426950408889634f;
constexpr float LN2   = 0.6931471805599453f;

__device__ __forceinline__ float exp2_fast(float v) {
#if defined(__has_builtin)
#if __has_builtin(__builtin_amdgcn_exp2f)
  return __builtin_amdgcn_exp2f(v);
#else
  return exp2f(v);
#endif
#else
  return exp2f(v);
#endif
}

// ---------------------------------------------------------------------------
// K_SORT (round-13 version, verbatim — measured win, sort computed once/b).
// ONE block per batch b (64 blocks x 1024 threads).  Writes prs (8KB) +
// desc (2KB) per b to workspace (L2-resident for the 16 softmax blocks).
// Zeroes d_out (block 0) for the tail layer's atomicAdds.
// ---------------------------------------------------------------------------
__global__ __launch_bounds__(1024) void k_sort(
    const float* __restrict__ x, float2* __restrict__ prs_g,
    float4* __restrict__ desc_g, float* __restrict__ out) {
  __shared__ float  xs_[Dn];
  __shared__ float2 prs_[Dn];
  __shared__ int    bkt_[Dn];
  __shared__ int   cnt[NBK], base_[NBK], off_[NBK];
  __shared__ float Ssum[NBK], cN[NBK], cS[NBK];

  int b   = blockIdx.x;
  int tid = threadIdx.x;

  if (tid < NBK) { cnt[tid] = 0; off_[tid] = 0; Ssum[tid] = 0.f; }
  if (b == 0 && tid < 128) out[tid] = 0.f;
  __syncthreads();

  // ---- bucket count (1 element per thread) ----
  float xv = x[b * Dn + tid];
  int bk;
  {
    float z = exp2_fast(-2.455532f * xv);      // 2^{-1.702 x log2e}, monotone
    float p = 1.f / (1.f + z);                 // ~Phi(x): near-uniform buckets
    int t = (int)(p * 128.f);
    bk = t < 0 ? 0 : (t > 127 ? 127 : t);
    atomicAdd(&cnt[bk], 1);
    atomicAdd(&Ssum[bk], xv);
  }
  __syncthreads();

  // ---- dual prefix scan over 128 buckets (wave 0, 2 buckets per lane) ----
  if (tid < 64) {
    int c0 = cnt[tid], c1 = cnt[tid + 64];
    float f0 = Ssum[tid], f1 = Ssum[tid + 64];
    int s0 = c0, s1 = c1;
    float g0 = f0, g1 = f1;
#pragma unroll
    for (int d = 1; d < 64; d <<= 1) {
      int o0 = __shfl_up(s0, d, 64), o1 = __shfl_up(s1, d, 64);
      float h0 = __shfl_up(g0, d, 64), h1 = __shfl_up(g1, d, 64);
      if (tid >= d) { s0 += o0; s1 += o1; g0 += h0; g1 += h1; }
    }
    int   T0 = __shfl(s0, 63, 64);
    float G0 = __shfl(g0, 63, 64);
    float G1 = __shfl(g1, 63, 64);
    float Stot = G0 + G1;
    int nlo0 = s0 - c0;
    base_[tid] = nlo0;
    cN[tid] = (float)(2 * nlo0 + c0 - Dn);     // Nlo - Nhi
    float slo0 = g0 - f0;
    cS[tid] = Stot - 2.f * slo0 - f0;          // Shi - Slo
    int nlo1 = T0 + s1 - c1;
    base_[tid + 64] = nlo1;
    cN[tid + 64] = (float)(2 * nlo1 + c1 - Dn);
    float slo1 = G0 + g1 - f1;
    cS[tid + 64] = Stot - 2.f * slo1 - f1;
  }
  __syncthreads();

  // ---- scatter ----
  {
    int pos = base_[bk] + atomicAdd(&off_[bk], 1);
    xs_[pos] = xv;
    bkt_[pos] = bk;
  }
  __syncthreads();

  // ---- exact Bsum per position (1 per thread; ~8-iter bucket loop) ----
  {
    float xp = xs_[tid];
    int q = bkt_[tid];
    int lo = base_[q], hi = lo + cnt[q];
    float local = 0.f;
    for (int k = lo; k < hi; ++k) local += fabsf(xp - xs_[k]);
    float Bs = fmaf(xp, cN[q], cS[q]) + local;
    float2 pr = make_float2(xp * LOG2E, -Bs * LOG2E);
    prs_[tid] = pr;
    prs_g[(size_t)b * Dn + tid] = pr;          // coalesced float2 store
  }
  __syncthreads();

  // ---- group descriptors (one group of 8 per thread, 128 groups) ----
  if (tid < 128) {
    int base = tid * 8;
    float xlo = xs_[base], xhi = xlo;
    int ilo = base, ihi = base;
#pragma unroll
    for (int k = 1; k < 8; ++k) {
      float xx = xs_[base + k];
      if (xx < xlo) { xlo = xx; ilo = base + k; }
      if (xx > xhi) { xhi = xx; ihi = base + k; }
    }
    float2 plo = prs_[ilo], phi = prs_[ihi];
    desc_g[b * 128 + tid] = make_float4(plo.x, plo.y, phi.x, phi.y);
  }
}

// ---------------------------------------------------------------------------
// K_SOFT v2: survivor loop reads prs as float4 (2 pair-entries per
// ds_read_b128, was 8x ds_read_b64 per group) — halves LDS issue in the hot
// loop and exposes 2 independent exps per read (trans-pipe ILP).
// Accumulation order preserved exactly (se += e0; se += e1 in the original
// u-sequence) -> bit-identical output.  Everything else round-13 verbatim.
// grid = 64 b x 16 rc = 1024 blocks of 512.
// ---------------------------------------------------------------------------
__global__ __launch_bounds__(512) void k_soft(
    const float2* __restrict__ prs_g, const float4* __restrict__ desc_g,
    float* __restrict__ xs_out) {
  __shared__ __align__(16) float2 prs_[Dn];
  __shared__ float4 desc_[128];
  __shared__ float redM[8][64], redE[8][64], redD[8][64];

  int b   = blockIdx.x >> 4;
  int rc  = blockIdx.x & 15;
  int tid = threadIdx.x;

  // ---- stage prs + desc into LDS ----
  ((float4*)prs_)[tid] = ((const float4*)(prs_g + (size_t)b * Dn))[tid];
  if (tid < 128) desc_[tid] = desc_g[b * 128 + tid];
  __syncthreads();

  int w = tid >> 6, lane = tid & 63;
  int i = rc * 64 + lane;
  float sc = (float)(Dn - 1 - 2 * i);          // exact in fp32
  float gm[16];
  float m = -3.4e38f;
#pragma unroll 8
  for (int q = 0; q < 16; ++q) {
    float4 d = desc_[q * 8 + w];               // wave-uniform broadcast
    float t0 = fmaf(sc, d.x, d.y);             // T at group's min-x element
    float t1 = fmaf(sc, d.z, d.w);             // T at group's max-x element
    float g = fmaxf(t0, t1);
    gm[q] = g;
    m = fmaxf(m, g);
  }
  redM[w][lane] = m;
  __syncthreads();
  float M = fmaxf(fmaxf(fmaxf(redM[0][lane], redM[1][lane]),
                        fmaxf(redM[2][lane], redM[3][lane])),
                  fmaxf(fmaxf(redM[4][lane], redM[5][lane]),
                        fmaxf(redM[6][lane], redM[7][lane])));
  float thresh = M - 32.f;

  const float4* pv = (const float4*)prs_;      // 2 pair-entries per float4
  float se = 0.f, sd = 0.f;
#pragma unroll 4
  for (int q = 0; q < 16; ++q) {
    if (__any(gm[q] > thresh)) {               // vote over 64 consecutive rows
      int base4 = (q * 8 + w) * 4;             // float4 index of group start
#pragma unroll
      for (int u = 0; u < 4; ++u) {
        float4 v = pv[base4 + u];              // wave-uniform broadcast
        float e0 = exp2_fast(fmaf(sc, v.x, v.y - M));
        float e1 = exp2_fast(fmaf(sc, v.z, v.w - M));
        se += e0;
        sd = fmaf(e0, v.x, sd);
        se += e1;
        sd = fmaf(e1, v.z, sd);
      }
    }
  }
  redE[w][lane] = se;
  redD[w][lane] = sd;
  __syncthreads();
  if (tid < 64) {
    float SE = ((redE[0][lane] + redE[1][lane]) + (redE[2][lane] + redE[3][lane])) +
               ((redE[4][lane] + redE[5][lane]) + (redE[6][lane] + redE[7][lane]));
    float SD = ((redD[0][lane] + redD[1][lane]) + (redD[2][lane] + redD[3][lane])) +
               ((redD[4][lane] + redD[5][lane]) + (redD[6][lane] + redD[7][lane]));
    xs_out[b * Dn + rc * 64 + lane] = SD / SE * LN2;
  }
}

// ---------------------------------------------------------------------------
// Layer kernel v4 (round-8 version, verbatim).
// h = leaky(in @ W^T + bias).  Block = 8 batches x 8 cols.  Wave =
// (col-quad cq = w&1, k-half kh = w>>1); lane owns 8 k-floats; 1 B/FMA LDS.
// W loaded exactly once per block.  5-level routed butterfly + rk combine.
// Granule XOR swizzle g^((g>>3)&7).  XCD swizzle.  TAIL fuses layer 3.
// ---------------------------------------------------------------------------
template <bool TAIL>
__global__ __launch_bounds__(256) void layer_kernel(
    const float* __restrict__ in, const float* __restrict__ W,
    const float* __restrict__ bias, float* __restrict__ out,
    const float* __restrict__ W3, const float* __restrict__ b3,
    float* __restrict__ out2) {
  __shared__ float s[8 * Dn];
  __shared__ float rk[4][32];
  __shared__ float r2[8][8][2];
  int xcd = blockIdx.x & 7;
  int idx = blockIdx.x >> 3;
  int nc = xcd * 16 + (idx & 15);
  int bc = idx >> 4;
  int tid = threadIdx.x;
  const float* src = in + bc * 8 * Dn;
#pragma unroll
  for (int u = 0; u < 8; ++u) {
    int gl = u * 256 + tid;
    int r = gl >> 8, g = gl & 255;
    int gs = g ^ ((g >> 3) & 7);
    *(float4*)&s[r * Dn + gs * 4] = *(const float4*)(src + gl * 4);
  }
  __syncthreads();

  int w = tid >> 6, lane = tid & 63;
  int cq = w & 1, kh = w >> 1;
  int n0 = nc * 8 + cq * 4;
  const float* wp = W + (size_t)n0 * Dn + kh * 512 + lane * 8;
  float acc[32];
#pragma unroll
  for (int i = 0; i < 32; ++i) acc[i] = 0.f;
#pragma unroll
  for (int j = 0; j < 2; ++j) {
    float4 wv0 = *(const float4*)(wp + 0 * Dn + j * 4);
    float4 wv1 = *(const float4*)(wp + 1 * Dn + j * 4);
    float4 wv2 = *(const float4*)(wp + 2 * Dn + j * 4);
    float4 wv3 = *(const float4*)(wp + 3 * Dn + j * 4);
    int g = kh * 128 + lane * 2 + j;
    int gs = g ^ ((g >> 3) & 7);
    const float* sp = s + gs * 4;
#pragma unroll
    for (int bl = 0; bl < 8; ++bl) {
      float4 av = *(const float4*)(sp + bl * Dn);
      acc[bl * 4 + 0] = fmaf(av.x, wv0.x, fmaf(av.y, wv0.y,
                        fmaf(av.z, wv0.z, fmaf(av.w, wv0.w, acc[bl * 4 + 0]))));
      acc[bl * 4 + 1] = fmaf(av.x, wv1.x, fmaf(av.y, wv1.y,
                        fmaf(av.z, wv1.z, fmaf(av.w, wv1.w, acc[bl * 4 + 1]))));
      acc[bl * 4 + 2] = fmaf(av.x, wv2.x, fmaf(av.y, wv2.y,
                        fmaf(av.z, wv2.z, fmaf(av.w, wv2.w, acc[bl * 4 + 2]))));
      acc[bl * 4 + 3] = fmaf(av.x, wv3.x, fmaf(av.y, wv3.y,
                        fmaf(av.z, wv3.z, fmaf(av.w, wv3.w, acc[bl * 4 + 3]))));
    }
  }

#pragma unroll
  for (int bit = 0; bit < 5; ++bit) {
    int d = 1 << bit;
    bool hi = (lane & d) != 0;
#pragma unroll
    for (int i = 0; i < (16 >> bit); ++i) {
      float keep = hi ? acc[2 * i + 1] : acc[2 * i];
      float send = hi ? acc[2 * i] : acc[2 * i + 1];
      acc[i] = keep + __shfl_xor(send, d, 64);
    }
  }
  float t = acc[0];
  t += __shfl_xor(t, 32, 64);
  if (lane < 32) rk[w][lane] = t;
  __syncthreads();

  if (tid < 64) {
    int bl2 = tid >> 3, col = tid & 7;
    int cq2 = col >> 2, cl2 = col & 3;
    int o = bl2 * 4 + cl2;
    int n2 = nc * 8 + col;
    float hs = rk[cq2][o] + rk[cq2 + 2][o];
    float h = hs + bias[n2];
    h = h >= 0.f ? h : 0.01f * h;
    if (!TAIL) {
      out[(bc * 8 + bl2) * Dn + n2] = h;
    } else {
      r2[bl2][col][0] = h * W3[n2];
      r2[bl2][col][1] = h * W3[Dn + n2];
    }
  }
  if (TAIL) {
    __syncthreads();
    if (tid < 16) {
      int bl2 = tid >> 1, o = tid & 1;
      float tt = 0.f;
#pragma unroll
      for (int q = 0; q < 8; ++q) tt += r2[bl2][q][o];
      if (nc == 0) tt += b3[o];
      atomicAdd(out2 + (bc * 8 + bl2) * 2 + o, tt);
    }
  }
}

extern "C" void kernel_launch(void* const* d_in, const int* in_sizes, int n_in,
                              void* d_out, int out_size, void* d_ws, size_t ws_size,
                              hipStream_t stream) {
  const float* x  = (const float*)d_in[0];
  const float* W1 = (const float*)d_in[1];
  const float* b1 = (const float*)d_in[2];
  const float* W2 = (const float*)d_in[3];
  const float* b2 = (const float*)d_in[4];
  const float* W3 = (const float*)d_in[5];
  const float* b3 = (const float*)d_in[6];
  float* out = (float*)d_out;
  float* ws = (float*)d_ws;

  float*  xs     = ws;                          // 256 KB
  float*  h1     = xs + Bn * Dn;                // 256 KB
  float2* prs_g  = (float2*)(h1 + Bn * Dn);     // 512 KB
  float4* desc_g = (float4*)(prs_g + Bn * Dn);  // 32 KB

  k_sort<<<Bn, 1024, 0, stream>>>(x, prs_g, desc_g, out);
  k_soft<<<Bn * 16, 512, 0, stream>>>(prs_g, desc_g, xs);
  layer_kernel<false><<<1024, 256, 0, stream>>>(xs, W1, b1, h1,
                                                nullptr, nullptr, nullptr);
  layer_kernel<true><<<1024, 256, 0, stream>>>(h1, W2, b2, nullptr,
                                               W3, b3, out);
}